// Round 5
// baseline (287.569 us; speedup 1.0000x reference)
//
#include <hip/hip_runtime.h>
#include <math.h>

#define B_N   8192
#define D_K   256
#define NGENE 200
#define MAXN  512
#define PCACHE 6144

typedef short  bf16x8 __attribute__((ext_vector_type(8)));
typedef float  f32x4  __attribute__((ext_vector_type(4)));

// ---- workspace layout (bytes), total 4,759,552 < proven 4.83MB ----
#define OFF_FNBF    0u          // 8192*256*2 = 4194304
#define OFF_LPART   4194304u    // bf16 [32][8192] = 524288
#define OFF_HIST    4718592u    // 256*4
#define OFF_OFFS    4719616u    // 256*4
#define OFF_SORTED  4720640u    // 8192*4 = 32768
#define OFF_CROSSP  4753408u    // 528*4 -> pad 4096
#define OFF_WITHINP 4757504u    // 256*4
#define OFF_CCORR   4758528u    // 256*4

__device__ __forceinline__ unsigned short f2bf(float f) {
    unsigned int u = __float_as_uint(f);
    unsigned int r = u + 0x7fffu + ((u >> 16) & 1u);
    return (unsigned short)(r >> 16);
}
__device__ __forceinline__ float bf2fu(unsigned short h) { return __uint_as_float(((unsigned int)h) << 16); }
__device__ __forceinline__ float bf2f_lo(unsigned int u) { return __uint_as_float(u << 16); }
__device__ __forceinline__ float bf2f_hi(unsigned int u) { return __uint_as_float(u & 0xffff0000u); }

// ---- kernel 1: normalize (blocks 0..2047) + hist/prefix/scatter (block 2048) ----
__global__ __launch_bounds__(256) void k_np(const float* __restrict__ feat,
                                            const int* __restrict__ lab,
                                            unsigned short* __restrict__ fnbf,
                                            int* __restrict__ hist,
                                            int* __restrict__ offs,
                                            int* __restrict__ sorted) {
    if (blockIdx.x < 2048) {
        int wave = threadIdx.x >> 6, lane = threadIdx.x & 63;
        int row  = blockIdx.x * 4 + wave;
        const float4* src = reinterpret_cast<const float4*>(feat + (size_t)row * D_K);
        float4 v = src[lane];
        float ss = v.x * v.x + v.y * v.y + v.z * v.z + v.w * v.w;
#pragma unroll
        for (int m = 1; m < 64; m <<= 1) ss += __shfl_xor(ss, m);
        float rn = 1.0f / sqrtf(ss);
        ushort4 o;
        o.x = f2bf(v.x * rn); o.y = f2bf(v.y * rn);
        o.z = f2bf(v.z * rn); o.w = f2bf(v.w * rn);
        reinterpret_cast<ushort4*>(fnbf + (size_t)row * D_K)[lane] = o;
        return;
    }
    // prep block
    __shared__ int sh_hist[256], sh_scan[256], sh_cur[256];
    int t = threadIdx.x;
    sh_hist[t] = 0;
    __syncthreads();
    for (int i = t; i < B_N; i += 256) {
        int lb = lab[i];
        if (lb >= 0 && lb < NGENE) atomicAdd(&sh_hist[lb], 1);
    }
    __syncthreads();
    int v = sh_hist[t];
    sh_scan[t] = v;
    __syncthreads();
#pragma unroll
    for (int d = 1; d < 256; d <<= 1) {
        int x = (t >= d) ? sh_scan[t - d] : 0;
        __syncthreads();
        sh_scan[t] += x;
        __syncthreads();
    }
    int excl = sh_scan[t] - v;
    sh_cur[t] = excl;
    if (t < NGENE) { hist[t] = v; offs[t] = excl; }
    __syncthreads();
    for (int i = t; i < B_N; i += 256) {
        int lb = lab[i];
        if (lb >= 0 && lb < NGENE) {
            int pos = atomicAdd(&sh_cur[lb], 1);
            sorted[pos] = i;
        }
    }
}

// asm-pinned A-fragment loads (compiler cannot rematerialize or sink)
#define GLOAD8(arr, vo) do {                                                                   \
    asm volatile("global_load_dwordx4 %0, %1, %2 offset:0"   : "=v"(arr[0]) : "v"(vo), "s"(fb)); \
    asm volatile("global_load_dwordx4 %0, %1, %2 offset:64"  : "=v"(arr[1]) : "v"(vo), "s"(fb)); \
    asm volatile("global_load_dwordx4 %0, %1, %2 offset:128" : "=v"(arr[2]) : "v"(vo), "s"(fb)); \
    asm volatile("global_load_dwordx4 %0, %1, %2 offset:192" : "=v"(arr[3]) : "v"(vo), "s"(fb)); \
    asm volatile("global_load_dwordx4 %0, %1, %2 offset:256" : "=v"(arr[4]) : "v"(vo), "s"(fb)); \
    asm volatile("global_load_dwordx4 %0, %1, %2 offset:320" : "=v"(arr[5]) : "v"(vo), "s"(fb)); \
    asm volatile("global_load_dwordx4 %0, %1, %2 offset:384" : "=v"(arr[6]) : "v"(vo), "s"(fb)); \
    asm volatile("global_load_dwordx4 %0, %1, %2 offset:448" : "=v"(arr[7]) : "v"(vo), "s"(fb)); \
} while (0)

#define Z4 ((f32x4){0.f, 0.f, 0.f, 0.f})

#define EPI(AC, LS, CE) do {                                    \
    _Pragma("unroll")                                           \
    for (int r = 0; r < 4; ++r) {                               \
        float av = AC[r];                                       \
        float e = exp2f(av * 2.8853900817779268f);              \
        LS[r] += e; CE += e;                                    \
        csum += fmaxf(av - 0.05f, 0.f);                         \
    }                                                           \
} while (0)

#define STEP(CUR, NXT, ST, DOSTAGE) do {                                              \
    int4 s0, s1, s2, s3;                                                              \
    if (DOSTAGE) {                                                                    \
        const char* gp = gtile + ((ST) + 1) * 16384;                                  \
        s0 = *(const int4*)(gp + srco[0]);                                            \
        s1 = *(const int4*)(gp + srco[1]);                                            \
        s2 = *(const int4*)(gp + srco[2]);                                            \
        s3 = *(const int4*)(gp + srco[3]);                                            \
    }                                                                                 \
    f32x4 acA0 = Z4, acA1 = Z4, acA2 = Z4, acA3 = Z4;                                 \
    f32x4 acB0 = Z4, acB1 = Z4, acB2 = Z4, acB3 = Z4;                                 \
    _Pragma("unroll")                                                                 \
    for (int ks = 0; ks < 8; ++ks) {                                                  \
        bf16x8 bv0 = *(const bf16x8*)(smem_c + (CUR) + ra[0][ks]);                    \
        bf16x8 bv1 = *(const bf16x8*)(smem_c + (CUR) + ra[1][ks]);                    \
        acA0 = __builtin_amdgcn_mfma_f32_16x16x32_bf16(a0[ks], bv0, acA0, 0, 0, 0);   \
        acA1 = __builtin_amdgcn_mfma_f32_16x16x32_bf16(a1[ks], bv0, acA1, 0, 0, 0);   \
        acA2 = __builtin_amdgcn_mfma_f32_16x16x32_bf16(a2[ks], bv0, acA2, 0, 0, 0);   \
        acA3 = __builtin_amdgcn_mfma_f32_16x16x32_bf16(a3[ks], bv0, acA3, 0, 0, 0);   \
        acB0 = __builtin_amdgcn_mfma_f32_16x16x32_bf16(a0[ks], bv1, acB0, 0, 0, 0);   \
        acB1 = __builtin_amdgcn_mfma_f32_16x16x32_bf16(a1[ks], bv1, acB1, 0, 0, 0);   \
        acB2 = __builtin_amdgcn_mfma_f32_16x16x32_bf16(a2[ks], bv1, acB2, 0, 0, 0);   \
        acB3 = __builtin_amdgcn_mfma_f32_16x16x32_bf16(a3[ks], bv1, acB3, 0, 0, 0);   \
    }                                                                                 \
    float ceA = 0.f, ceB = 0.f;                                                       \
    EPI(acA0, lsum[0], ceA); EPI(acA1, lsum[1], ceA);                                 \
    EPI(acA2, lsum[2], ceA); EPI(acA3, lsum[3], ceA);                                 \
    EPI(acB0, lsum[0], ceB); EPI(acB1, lsum[1], ceB);                                 \
    EPI(acB2, lsum[2], ceB); EPI(acB3, lsum[3], ceB);                                 \
    ceA += __shfl_xor(ceA, 16); ceA += __shfl_xor(ceA, 32);                           \
    ceB += __shfl_xor(ceB, 16); ceB += __shfl_xor(ceB, 32);                           \
    if (lane < 16) {                                                                  \
        colsumws[wave * 256 + (ST) * 32 + lane] += ceA;                               \
        colsumws[wave * 256 + (ST) * 32 + 16 + lane] += ceB;                          \
    }                                                                                 \
    if (DOSTAGE) {                                                                    \
        *(int4*)(smem_c + (NXT) + dsto[0]) = s0;                                      \
        *(int4*)(smem_c + (NXT) + dsto[1]) = s1;                                      \
        *(int4*)(smem_c + (NXT) + dsto[2]) = s2;                                      \
        *(int4*)(smem_c + (NXT) + dsto[3]) = s3;                                      \
    }                                                                                 \
    __syncthreads();                                                                  \
} while (0)

// ---- kernel 2: symmetric fused pairwise pass over upper-triangle 256x256 blocks ----
// block = 4 waves x 64 rows = 256 rows x 256 cols, LDS-staged B (32 cols/step, dbuf, XOR-swizzled)
__global__ __launch_bounds__(256, 2) void k_pairwise(const unsigned short* __restrict__ fnbf,
                                                     unsigned short* __restrict__ l_part,
                                                     float* __restrict__ cross_part) {
    __shared__ __align__(16) char smem_c[36864];   // 2x16KB B dbuf + 4KB colsum
    float* colsumws = (float*)(smem_c + 32768);

    int wave = threadIdx.x >> 6, lane = threadIdx.x & 63;
    int g16 = lane >> 4, l16 = lane & 15;

    int b = blockIdx.x, rg = 0, rem = b;
    while (rem >= 32 - rg) { rem -= 32 - rg; ++rg; }
    int cw = rg + rem;                       // rg <= cw (upper triangle)

    int r0 = rg * 256 + wave * 64;
    const unsigned short* fb = fnbf;
    const char* gtile = (const char*)fnbf + (size_t)cw * 131072u;

    // zero own colsum row (wave-private, no barrier needed before own rmw)
#pragma unroll
    for (int k = 0; k < 4; ++k) colsumws[wave * 256 + lane * 4 + k] = 0.f;

    // A fragments: 4 row-tiles x 8 k-slices = 128 VGPRs, asm-pinned
    bf16x8 a0[8], a1[8], a2[8], a3[8];
    unsigned voa = (unsigned)(r0 + l16) * 512u + (unsigned)g16 * 16u;
    GLOAD8(a0, voa); voa += 16u * 512u;
    GLOAD8(a1, voa); voa += 16u * 512u;
    GLOAD8(a2, voa); voa += 16u * 512u;
    GLOAD8(a3, voa);

    // staging offsets: linear LDS dest slot s -> (col cl = s>>5, chunk' = s&31),
    // source chunk c = chunk' ^ (cl&15)  (inverse-swizzled source, rule 21)
    int srco[4], dsto[4];
    int sbase = wave * 256 + lane;
#pragma unroll
    for (int k = 0; k < 4; ++k) {
        int s = sbase + k * 64;
        int cl = s >> 5, chp = s & 31;
        srco[k] = cl * 512 + (chp ^ (cl & 15)) * 16;
        dsto[k] = s * 16;
    }
    // ds_read offsets: col (nt*16+l16), chunk (g16+4ks) stored at chunk^l16 -> 2-way banks (free)
    int ra[2][8];
#pragma unroll
    for (int nt = 0; nt < 2; ++nt)
#pragma unroll
        for (int ks = 0; ks < 8; ++ks)
            ra[nt][ks] = (nt * 16 + l16) * 512 + (((g16 + 4 * ks) ^ l16) & 31) * 16;

    // prologue: stage tile 0 into buffer 0
    {
        int4 t0 = *(const int4*)(gtile + srco[0]);
        int4 t1 = *(const int4*)(gtile + srco[1]);
        int4 t2 = *(const int4*)(gtile + srco[2]);
        int4 t3 = *(const int4*)(gtile + srco[3]);
        *(int4*)(smem_c + dsto[0]) = t0;
        *(int4*)(smem_c + dsto[1]) = t1;
        *(int4*)(smem_c + dsto[2]) = t2;
        *(int4*)(smem_c + dsto[3]) = t3;
    }
    asm volatile("s_waitcnt vmcnt(0)" ::: "memory");
    __builtin_amdgcn_sched_barrier(0);
    __syncthreads();

    float lsum[4][4] = {};
    float csum = 0.f;

    STEP(0,     16384, 0, 1);
    STEP(16384, 0,     1, 1);
    STEP(0,     16384, 2, 1);
    STEP(16384, 0,     3, 1);
    STEP(0,     16384, 4, 1);
    STEP(16384, 0,     5, 1);
    STEP(0,     16384, 6, 1);
    STEP(16384, 0,     7, 0);

    // column sums -> l_part[rg][cw*256 + col]  (mirror rows; off-diagonal blocks only)
    if (rg < cw) {
        int tcol = threadIdx.x;
        float cs = colsumws[tcol] + colsumws[256 + tcol] + colsumws[512 + tcol] + colsumws[768 + tcol];
        l_part[(size_t)rg * B_N + cw * 256 + tcol] = f2bf(cs);
    }

    // row sums -> l_part[cw][row]
#pragma unroll
    for (int t = 0; t < 4; ++t)
#pragma unroll
        for (int r = 0; r < 4; ++r) {
            float v = lsum[t][r];
            v += __shfl_xor(v, 1); v += __shfl_xor(v, 2);
            v += __shfl_xor(v, 4); v += __shfl_xor(v, 8);
            if (l16 == 0)
                l_part[(size_t)cw * B_N + r0 + t * 16 + g16 * 4 + r] = f2bf(v);
        }

    // cross partial (half-relu units); off-diagonal blocks count both orders
    float c = csum;
#pragma unroll
    for (int m = 1; m < 64; m <<= 1) c += __shfl_xor(c, m);
    __shared__ float shcr[4];
    if (lane == 0) shcr[wave] = c;
    __syncthreads();
    if (threadIdx.x == 0) {
        float tot = shcr[0] + shcr[1] + shcr[2] + shcr[3];
        cross_part[b] = (rg < cw) ? 2.0f * tot : tot;
    }
}

__device__ __forceinline__ float dot_rows(const uint4* __restrict__ fu, int i, int j) {
    const uint4* pa = fu + (size_t)i * 16;
    const uint4* pb = fu + (size_t)j * 16;
    float d = 0.f;
#pragma unroll
    for (int k = 0; k < 16; ++k) {
        uint4 ua = pa[k], ub = pb[k];
        d = fmaf(bf2f_lo(ua.x), bf2f_lo(ub.x), d);
        d = fmaf(bf2f_hi(ua.x), bf2f_hi(ub.x), d);
        d = fmaf(bf2f_lo(ua.y), bf2f_lo(ub.y), d);
        d = fmaf(bf2f_hi(ua.y), bf2f_hi(ub.y), d);
        d = fmaf(bf2f_lo(ua.z), bf2f_lo(ub.z), d);
        d = fmaf(bf2f_hi(ua.z), bf2f_hi(ub.z), d);
        d = fmaf(bf2f_lo(ua.w), bf2f_lo(ub.w), d);
        d = fmaf(bf2f_hi(ua.w), bf2f_hi(ub.w), d);
    }
    return d;
}

// ---- kernel 3: per-gene corrections + lse + within-gene loss ----
__global__ __launch_bounds__(256) void k_within(const unsigned short* __restrict__ fnbf,
                                                const int* __restrict__ hist,
                                                const int* __restrict__ offs,
                                                const int* __restrict__ sorted,
                                                const unsigned short* __restrict__ l_part,
                                                float* __restrict__ within_part,
                                                float* __restrict__ cross_corr) {
    int g = blockIdx.x;
    int n = hist[g], start = offs[g];
    int t = threadIdx.x;
    __shared__ int   rid[MAXN];
    __shared__ float rexp[MAXN];
    __shared__ float slse[MAXN];
    __shared__ float pdot[PCACHE];
    __shared__ float red[256];

    const uint4* fu = reinterpret_cast<const uint4*>(fnbf);
    float ccor = 0.f;

    // phase 1: raw exp-sum (32 bf16 chunks) minus diagonal; diag cross correction
    for (int idx = t; idx < n; idx += 256) {
        int row = sorted[start + idx];
        rid[idx] = row;
        float raw = 0.f;
#pragma unroll
        for (int k = 0; k < 32; ++k) raw += bf2fu(l_part[(size_t)k * B_N + row]);
        float ss = dot_rows(fu, row, row);
        ccor += fmaxf(2.0f * ss - 0.1f, 0.f);
        rexp[idx] = raw - __expf(2.0f * ss);
    }
    __syncthreads();

    int P = n * (n - 1) / 2;

    // phase A: subtract same-gene pair exps (cache dots); cross correction
    for (int p = t; p < P; p += 256) {
        int aa = 0, pp = p, span = n - 1;
        while (pp >= span) { pp -= span; ++aa; --span; }
        int bb = aa + 1 + pp;
        float d = dot_rows(fu, rid[aa], rid[bb]);
        if (p < PCACHE) pdot[p] = d;
        float e = __expf(2.0f * d);
        atomicAdd(&rexp[aa], -e);
        atomicAdd(&rexp[bb], -e);
        ccor += 2.0f * fmaxf(2.0f * d - 0.1f, 0.f);
    }
    __syncthreads();

    // phase B: lse per row (every row has negatives since B_N - n > 0)
    for (int idx = t; idx < n; idx += 256)
        slse[idx] = __logf(rexp[idx]);
    __syncthreads();

    // phase 2: softplus over pairs, anchor = smaller row index
    float wsum = 0.f;
    for (int p = t; p < P; p += 256) {
        int aa = 0, pp = p, span = n - 1;
        while (pp >= span) { pp -= span; ++aa; --span; }
        int bb = aa + 1 + pp;
        int ia = rid[aa], ib = rid[bb];
        float d = (p < PCACHE) ? pdot[p] : dot_rows(fu, ia, ib);
        int ai = (ia < ib) ? aa : bb;
        float x = slse[ai] - 2.0f * d;
        wsum += fmaxf(x, 0.f) + log1pf(__expf(-fabsf(x)));
    }

    red[t] = wsum;
    __syncthreads();
#pragma unroll
    for (int d2 = 128; d2 > 0; d2 >>= 1) {
        if (t < d2) red[t] += red[t + d2];
        __syncthreads();
    }
    if (t == 0) within_part[g] = red[0];
    __syncthreads();
    red[t] = ccor;
    __syncthreads();
#pragma unroll
    for (int d2 = 128; d2 > 0; d2 >>= 1) {
        if (t < d2) red[t] += red[t + d2];
        __syncthreads();
    }
    if (t == 0) cross_corr[g] = red[0];
}

// ---- kernel 4: final reduction + outputs ----
__global__ __launch_bounds__(256) void k_finalize(const float* __restrict__ cross_part,
                                                  const float* __restrict__ within_part,
                                                  const float* __restrict__ cross_corr,
                                                  const int* __restrict__ hist,
                                                  float* __restrict__ out) {
    __shared__ float shc[256];
    __shared__ float shw[256];
    __shared__ float shk[256];
    __shared__ long long shs[256];
    int t = threadIdx.x;
    float cs = 0.f;
    for (int i = t; i < 528; i += 256) cs += cross_part[i];
    float wv = 0.f, cc = 0.f;
    long long s2 = 0;
    if (t < NGENE) {
        wv = within_part[t];
        cc = cross_corr[t];
        long long h = hist[t];
        s2 = h * h;
    }
    shc[t] = cs; shw[t] = wv; shk[t] = cc; shs[t] = s2;
    __syncthreads();
#pragma unroll
    for (int d = 128; d > 0; d >>= 1) {
        if (t < d) {
            shc[t] += shc[t + d]; shw[t] += shw[t + d];
            shk[t] += shk[t + d]; shs[t] += shs[t + d];
        }
        __syncthreads();
    }
    if (t == 0) {
        long long S  = shs[0];
        long long nw = S - (long long)B_N;
        long long nc = (long long)B_N * (long long)B_N - S;
        float cross_total = 2.0f * shc[0] - shk[0];   // csum was half-relu units
        float cross_loss = (nc > 0) ? (cross_total / (float)(nc > 1 ? nc : 1)) : 0.f;
        float within     = shw[0];
        out[0] = within + 0.5f * cross_loss;
        out[1] = within;
        out[2] = cross_loss;
        out[3] = (float)nw;
        out[4] = (float)nc;
    }
}

extern "C" void kernel_launch(void* const* d_in, const int* in_sizes, int n_in,
                              void* d_out, int out_size, void* d_ws, size_t ws_size,
                              hipStream_t stream) {
    const float* feat = (const float*)d_in[0];
    const int*   lab  = (const int*)d_in[1];
    float* out = (float*)d_out;
    char* ws = (char*)d_ws;

    unsigned short* fnbf   = (unsigned short*)(ws + OFF_FNBF);
    unsigned short* l_part = (unsigned short*)(ws + OFF_LPART);
    int*   hist            = (int*)(ws + OFF_HIST);
    int*   offs            = (int*)(ws + OFF_OFFS);
    int*   sorted          = (int*)(ws + OFF_SORTED);
    float* cross_part      = (float*)(ws + OFF_CROSSP);
    float* within_part     = (float*)(ws + OFF_WITHINP);
    float* cross_corr      = (float*)(ws + OFF_CCORR);

    k_np<<<2049, 256, 0, stream>>>(feat, lab, fnbf, hist, offs, sorted);
    k_pairwise<<<528, 256, 0, stream>>>(fnbf, l_part, cross_part);
    k_within<<<NGENE, 256, 0, stream>>>(fnbf, hist, offs, sorted, l_part, within_part, cross_corr);
    k_finalize<<<1, 256, 0, stream>>>(cross_part, within_part, cross_corr, hist, out);
}

// Round 6
// 113.002 us; speedup vs baseline: 2.5448x; 2.5448x over previous
//
#include <hip/hip_runtime.h>
#include <math.h>

#define B_N   8192
#define D_K   256
#define NGENE 200
#define MAXN  512
#define PCACHE 6144

typedef short  bf16x8 __attribute__((ext_vector_type(8)));
typedef float  f32x4  __attribute__((ext_vector_type(4)));

// ---- workspace layout (bytes), total 4,757,504 (proven size) ----
#define OFF_FNBF    0u          // 8192*256*2 = 4194304
#define OFF_LPART   4194304u    // f32 [16][8192] = 524288
#define OFF_HIST    4718592u    // 256*4
#define OFF_OFFS    4719616u    // 256*4
#define OFF_SORTED  4720640u    // 8192*4
#define OFF_CROSSP  4753408u    // 512*4
#define OFF_WITHINP 4755456u    // 256*4
#define OFF_CCORR   4756480u    // 256*4

__device__ __forceinline__ unsigned short f2bf(float f) {
    unsigned int u = __float_as_uint(f);
    unsigned int r = u + 0x7fffu + ((u >> 16) & 1u);
    return (unsigned short)(r >> 16);
}
__device__ __forceinline__ float bf2f_lo(unsigned int u) { return __uint_as_float(u << 16); }
__device__ __forceinline__ float bf2f_hi(unsigned int u) { return __uint_as_float(u & 0xffff0000u); }

// ---- kernel 1: normalize (blocks 0..2047) + hist/prefix/scatter (block 2048) ----
__global__ __launch_bounds__(256) void k_np(const float* __restrict__ feat,
                                            const int* __restrict__ lab,
                                            unsigned short* __restrict__ fnbf,
                                            int* __restrict__ hist,
                                            int* __restrict__ offs,
                                            int* __restrict__ sorted) {
    if (blockIdx.x < 2048) {
        int wave = threadIdx.x >> 6, lane = threadIdx.x & 63;
        int row  = blockIdx.x * 4 + wave;
        const float4* src = reinterpret_cast<const float4*>(feat + (size_t)row * D_K);
        float4 v = src[lane];
        float ss = v.x * v.x + v.y * v.y + v.z * v.z + v.w * v.w;
#pragma unroll
        for (int m = 1; m < 64; m <<= 1) ss += __shfl_xor(ss, m);
        float rn = 1.0f / sqrtf(ss);
        ushort4 o;
        o.x = f2bf(v.x * rn); o.y = f2bf(v.y * rn);
        o.z = f2bf(v.z * rn); o.w = f2bf(v.w * rn);
        reinterpret_cast<ushort4*>(fnbf + (size_t)row * D_K)[lane] = o;
        return;
    }
    __shared__ int sh_hist[256], sh_scan[256], sh_cur[256];
    int t = threadIdx.x;
    sh_hist[t] = 0;
    __syncthreads();
    for (int i = t; i < B_N; i += 256) {
        int lb = lab[i];
        if (lb >= 0 && lb < NGENE) atomicAdd(&sh_hist[lb], 1);
    }
    __syncthreads();
    int v = sh_hist[t];
    sh_scan[t] = v;
    __syncthreads();
#pragma unroll
    for (int d = 1; d < 256; d <<= 1) {
        int x = (t >= d) ? sh_scan[t - d] : 0;
        __syncthreads();
        sh_scan[t] += x;
        __syncthreads();
    }
    int excl = sh_scan[t] - v;
    sh_cur[t] = excl;
    if (t < NGENE) { hist[t] = v; offs[t] = excl; }
    __syncthreads();
    for (int i = t; i < B_N; i += 256) {
        int lb = lab[i];
        if (lb >= 0 && lb < NGENE) {
            int pos = atomicAdd(&sh_cur[lb], 1);
            sorted[pos] = i;
        }
    }
}

// asm-pinned A-fragment loads (compiler cannot rematerialize or sink)
#define GLOAD8(arr, vo) do {                                                                   \
    asm volatile("global_load_dwordx4 %0, %1, %2 offset:0"   : "=v"(arr[0]) : "v"(vo), "s"(fb)); \
    asm volatile("global_load_dwordx4 %0, %1, %2 offset:64"  : "=v"(arr[1]) : "v"(vo), "s"(fb)); \
    asm volatile("global_load_dwordx4 %0, %1, %2 offset:128" : "=v"(arr[2]) : "v"(vo), "s"(fb)); \
    asm volatile("global_load_dwordx4 %0, %1, %2 offset:192" : "=v"(arr[3]) : "v"(vo), "s"(fb)); \
    asm volatile("global_load_dwordx4 %0, %1, %2 offset:256" : "=v"(arr[4]) : "v"(vo), "s"(fb)); \
    asm volatile("global_load_dwordx4 %0, %1, %2 offset:320" : "=v"(arr[5]) : "v"(vo), "s"(fb)); \
    asm volatile("global_load_dwordx4 %0, %1, %2 offset:384" : "=v"(arr[6]) : "v"(vo), "s"(fb)); \
    asm volatile("global_load_dwordx4 %0, %1, %2 offset:448" : "=v"(arr[7]) : "v"(vo), "s"(fb)); \
} while (0)

// async global->LDS, 16B per lane, zero VGPR result cost
#define GL_LDS16(gp, lp)                                                          \
    __builtin_amdgcn_global_load_lds(                                             \
        (const __attribute__((address_space(1))) unsigned int*)(gp),              \
        (__attribute__((address_space(3))) unsigned int*)(lp), 16, 0, 0)

#define Z4 ((f32x4){0.f, 0.f, 0.f, 0.f})
#define MFMA(A, B, C) __builtin_amdgcn_mfma_f32_16x16x32_bf16(A, B, C, 0, 0, 0)

#define EPI(AC, LS) do {                                        \
    _Pragma("unroll")                                           \
    for (int r = 0; r < 4; ++r) {                               \
        float av = AC[r];                                       \
        LS[r] += __expf(2.0f * av);                             \
        csum += fmaxf(av - 0.05f, 0.f);                         \
    }                                                           \
} while (0)

#define STAGE(BUF) do {                    \
    GL_LDS16(g0, smem_c + (BUF) + st0);    \
    GL_LDS16(g1, smem_c + (BUF) + st1);    \
    GL_LDS16(g2, smem_c + (BUF) + st2);    \
    GL_LDS16(g3, smem_c + (BUF) + st3);    \
    g0 += 16384; g1 += 16384; g2 += 16384; g3 += 16384; \
} while (0)

// ---- kernel 2: fused pairwise pass, B staged via global_load_lds (dbuf LDS) ----
// block = 4 waves x 64 rows = 256 rows, 512-col window, 16 steps x 32 cols
__global__ __launch_bounds__(256, 2) void k_pairwise(const unsigned short* __restrict__ fnbf,
                                                     float* __restrict__ l_part,
                                                     float* __restrict__ cross_part) {
    __shared__ __align__(16) char smem_c[32768];   // 2 x 16KB B tile

    int wave = threadIdx.x >> 6, lane = threadIdx.x & 63;
    int g16 = lane >> 4, l16 = lane & 15;
    int l7 = l16 & 7;
    int rg = blockIdx.x, cwin = blockIdx.y;
    int r0 = rg * 256 + wave * 64;
    const unsigned short* fb = fnbf;

    // A fragments pinned: 4 row-tiles x 8 k-slices = 128 VGPRs
    bf16x8 a0[8], a1[8], a2[8], a3[8];
    unsigned voa = (unsigned)(r0 + l16) * 512u + (unsigned)g16 * 16u;
    GLOAD8(a0, voa); voa += 16u * 512u;
    GLOAD8(a1, voa); voa += 16u * 512u;
    GLOAD8(a2, voa); voa += 16u * 512u;
    GLOAD8(a3, voa);

    // staging: tile = 32 cols x 512B. Linear LDS slot f = col*32 + s holds global
    // chunk c = s ^ ((col&7)<<2)  (inverse-swizzled source, linear dest).
    // 4 issues/wave, 1KB each: flat f = (wave*4+q)*64 + lane.
    const char* gwin = (const char*)fnbf + (size_t)cwin * 262144u;  // col-window base
    const char *g0, *g1, *g2, *g3;
    {
        int f0 = (wave * 4 + 0) * 64 + lane;
        int f1 = f0 + 64, f2 = f0 + 128, f3 = f0 + 192;
        int c0 = f0 >> 5, c1 = f1 >> 5, c2 = f2 >> 5, c3 = f3 >> 5;
        g0 = gwin + c0 * 512 + ((f0 & 31) ^ ((c0 & 7) << 2)) * 16;
        g1 = gwin + c1 * 512 + ((f1 & 31) ^ ((c1 & 7) << 2)) * 16;
        g2 = gwin + c2 * 512 + ((f2 & 31) ^ ((c2 & 7) << 2)) * 16;
        g3 = gwin + c3 * 512 + ((f3 & 31) ^ ((c3 & 7) << 2)) * 16;
    }
    unsigned st0 = (wave * 4 + 0) * 1024u, st1 = st0 + 1024u,
             st2 = st0 + 2048u, st3 = st0 + 3072u;

    // prologue: stage tile 0 into buffer 0; wait for A + tile 0
    STAGE(0u);
    asm volatile("s_waitcnt vmcnt(0)" ::: "memory");
    __builtin_amdgcn_sched_barrier(0);
    __syncthreads();

    float lsum[4][4] = {};
    float csum = 0.f;
    int vb = l16 * 512 + g16 * 16;

    unsigned cur = 0;
#pragma unroll 1
    for (int st = 0; st < 16; ++st) {
        if (st < 15) STAGE(cur ^ 16384u);

        f32x4 acA0 = Z4, acA1 = Z4, acA2 = Z4, acA3 = Z4;
        f32x4 acB0 = Z4, acB1 = Z4, acB2 = Z4, acB3 = Z4;
#pragma unroll
        for (int ks = 0; ks < 8; ++ks) {
            const char* p = smem_c + cur + (unsigned)(vb + ((ks ^ l7) << 6));
            bf16x8 bv0 = *(const bf16x8*)p;
            bf16x8 bv1 = *(const bf16x8*)(p + 8192);
            acA0 = MFMA(a0[ks], bv0, acA0);
            acA1 = MFMA(a1[ks], bv0, acA1);
            acA2 = MFMA(a2[ks], bv0, acA2);
            acA3 = MFMA(a3[ks], bv0, acA3);
            acB0 = MFMA(a0[ks], bv1, acB0);
            acB1 = MFMA(a1[ks], bv1, acB1);
            acB2 = MFMA(a2[ks], bv1, acB2);
            acB3 = MFMA(a3[ks], bv1, acB3);
        }
        EPI(acA0, lsum[0]); EPI(acA1, lsum[1]); EPI(acA2, lsum[2]); EPI(acA3, lsum[3]);
        EPI(acB0, lsum[0]); EPI(acB1, lsum[1]); EPI(acB2, lsum[2]); EPI(acB3, lsum[3]);

        asm volatile("s_waitcnt vmcnt(0)" ::: "memory");
        __builtin_amdgcn_sched_barrier(0);
        __syncthreads();
        cur ^= 16384u;
    }

    // reduce exp-sums across the 16 lanes sharing each output row
#pragma unroll
    for (int t = 0; t < 4; ++t)
#pragma unroll
        for (int r = 0; r < 4; ++r) {
            float v = lsum[t][r];
            v += __shfl_xor(v, 1); v += __shfl_xor(v, 2);
            v += __shfl_xor(v, 4); v += __shfl_xor(v, 8);
            if (l16 == 0)
                l_part[(size_t)cwin * B_N + r0 + t * 16 + g16 * 4 + r] = v;
        }

    // block-reduce half-relu sum
    float c = csum;
#pragma unroll
    for (int m = 1; m < 64; m <<= 1) c += __shfl_xor(c, m);
    __shared__ float shc[4];
    if (lane == 0) shc[wave] = c;
    __syncthreads();
    if (threadIdx.x == 0)
        cross_part[cwin * 32 + rg] = shc[0] + shc[1] + shc[2] + shc[3];
}

__device__ __forceinline__ float dot_rows(const uint4* __restrict__ fu, int i, int j) {
    const uint4* pa = fu + (size_t)i * 16;
    const uint4* pb = fu + (size_t)j * 16;
    float d = 0.f;
#pragma unroll
    for (int k = 0; k < 16; ++k) {
        uint4 ua = pa[k], ub = pb[k];
        d = fmaf(bf2f_lo(ua.x), bf2f_lo(ub.x), d);
        d = fmaf(bf2f_hi(ua.x), bf2f_hi(ub.x), d);
        d = fmaf(bf2f_lo(ua.y), bf2f_lo(ub.y), d);
        d = fmaf(bf2f_hi(ua.y), bf2f_hi(ub.y), d);
        d = fmaf(bf2f_lo(ua.z), bf2f_lo(ub.z), d);
        d = fmaf(bf2f_hi(ua.z), bf2f_hi(ub.z), d);
        d = fmaf(bf2f_lo(ua.w), bf2f_lo(ub.w), d);
        d = fmaf(bf2f_hi(ua.w), bf2f_hi(ub.w), d);
    }
    return d;
}

// ---- kernel 3: per-gene corrections + lse + within-gene loss ----
__global__ __launch_bounds__(256) void k_within(const unsigned short* __restrict__ fnbf,
                                                const int* __restrict__ hist,
                                                const int* __restrict__ offs,
                                                const int* __restrict__ sorted,
                                                const float* __restrict__ l_part,
                                                float* __restrict__ within_part,
                                                float* __restrict__ cross_corr) {
    int g = blockIdx.x;
    int n = hist[g], start = offs[g];
    int t = threadIdx.x;
    __shared__ int   rid[MAXN];
    __shared__ float rexp[MAXN];
    __shared__ float slse[MAXN];
    __shared__ float pdot[PCACHE];
    __shared__ float red[256];

    const uint4* fu = reinterpret_cast<const uint4*>(fnbf);
    float ccor = 0.f;

    // phase 1: raw exp-sum minus diagonal; diag cross correction
    for (int idx = t; idx < n; idx += 256) {
        int row = sorted[start + idx];
        rid[idx] = row;
        float raw = 0.f;
#pragma unroll
        for (int k = 0; k < 16; ++k) raw += l_part[(size_t)k * B_N + row];
        float ss = dot_rows(fu, row, row);
        ccor += fmaxf(2.0f * ss - 0.1f, 0.f);
        rexp[idx] = raw - __expf(2.0f * ss);
    }
    __syncthreads();

    int P = n * (n - 1) / 2;

    // phase A: subtract same-gene pair exps (cache dots); cross correction
    for (int p = t; p < P; p += 256) {
        int aa = 0, pp = p, span = n - 1;
        while (pp >= span) { pp -= span; ++aa; --span; }
        int bb = aa + 1 + pp;
        float d = dot_rows(fu, rid[aa], rid[bb]);
        if (p < PCACHE) pdot[p] = d;
        float e = __expf(2.0f * d);
        atomicAdd(&rexp[aa], -e);
        atomicAdd(&rexp[bb], -e);
        ccor += 2.0f * fmaxf(2.0f * d - 0.1f, 0.f);
    }
    __syncthreads();

    // phase B: lse per row (every row has negatives since B_N - n > 0)
    for (int idx = t; idx < n; idx += 256)
        slse[idx] = __logf(rexp[idx]);
    __syncthreads();

    // phase 2: softplus over pairs, anchor = smaller row index
    float wsum = 0.f;
    for (int p = t; p < P; p += 256) {
        int aa = 0, pp = p, span = n - 1;
        while (pp >= span) { pp -= span; ++aa; --span; }
        int bb = aa + 1 + pp;
        int ia = rid[aa], ib = rid[bb];
        float d = (p < PCACHE) ? pdot[p] : dot_rows(fu, ia, ib);
        int ai = (ia < ib) ? aa : bb;
        float x = slse[ai] - 2.0f * d;
        wsum += fmaxf(x, 0.f) + log1pf(__expf(-fabsf(x)));
    }

    red[t] = wsum;
    __syncthreads();
#pragma unroll
    for (int d2 = 128; d2 > 0; d2 >>= 1) {
        if (t < d2) red[t] += red[t + d2];
        __syncthreads();
    }
    if (t == 0) within_part[g] = red[0];
    __syncthreads();
    red[t] = ccor;
    __syncthreads();
#pragma unroll
    for (int d2 = 128; d2 > 0; d2 >>= 1) {
        if (t < d2) red[t] += red[t + d2];
        __syncthreads();
    }
    if (t == 0) cross_corr[g] = red[0];
}

// ---- kernel 4: final reduction + outputs ----
__global__ __launch_bounds__(256) void k_finalize(const float* __restrict__ cross_part,
                                                  const float* __restrict__ within_part,
                                                  const float* __restrict__ cross_corr,
                                                  const int* __restrict__ hist,
                                                  float* __restrict__ out) {
    __shared__ float shc[256];
    __shared__ float shw[256];
    __shared__ float shk[256];
    __shared__ long long shs[256];
    int t = threadIdx.x;
    float cs = 0.f;
    for (int i = t; i < 512; i += 256) cs += cross_part[i];
    float wv = 0.f, cc = 0.f;
    long long s2 = 0;
    if (t < NGENE) {
        wv = within_part[t];
        cc = cross_corr[t];
        long long h = hist[t];
        s2 = h * h;
    }
    shc[t] = cs; shw[t] = wv; shk[t] = cc; shs[t] = s2;
    __syncthreads();
#pragma unroll
    for (int d = 128; d > 0; d >>= 1) {
        if (t < d) {
            shc[t] += shc[t + d]; shw[t] += shw[t + d];
            shk[t] += shk[t + d]; shs[t] += shs[t + d];
        }
        __syncthreads();
    }
    if (t == 0) {
        long long S  = shs[0];
        long long nw = S - (long long)B_N;
        long long nc = (long long)B_N * (long long)B_N - S;
        float cross_total = 2.0f * shc[0] - shk[0];   // csum was half-relu units
        float cross_loss = (nc > 0) ? (cross_total / (float)(nc > 1 ? nc : 1)) : 0.f;
        float within     = shw[0];
        out[0] = within + 0.5f * cross_loss;
        out[1] = within;
        out[2] = cross_loss;
        out[3] = (float)nw;
        out[4] = (float)nc;
    }
}

extern "C" void kernel_launch(void* const* d_in, const int* in_sizes, int n_in,
                              void* d_out, int out_size, void* d_ws, size_t ws_size,
                              hipStream_t stream) {
    const float* feat = (const float*)d_in[0];
    const int*   lab  = (const int*)d_in[1];
    float* out = (float*)d_out;
    char* ws = (char*)d_ws;

    unsigned short* fnbf = (unsigned short*)(ws + OFF_FNBF);
    float* l_part        = (float*)(ws + OFF_LPART);
    int*   hist          = (int*)(ws + OFF_HIST);
    int*   offs          = (int*)(ws + OFF_OFFS);
    int*   sorted        = (int*)(ws + OFF_SORTED);
    float* cross_part    = (float*)(ws + OFF_CROSSP);
    float* within_part   = (float*)(ws + OFF_WITHINP);
    float* cross_corr    = (float*)(ws + OFF_CCORR);

    k_np<<<2049, 256, 0, stream>>>(feat, lab, fnbf, hist, offs, sorted);
    k_pairwise<<<dim3(32, 16), 256, 0, stream>>>(fnbf, l_part, cross_part);
    k_within<<<NGENE, 256, 0, stream>>>(fnbf, hist, offs, sorted, l_part, within_part, cross_corr);
    k_finalize<<<1, 256, 0, stream>>>(cross_part, within_part, cross_corr, hist, out);
}